// Round 16
// baseline (111.156 us; speedup 1.0000x reference)
//
#include <hip/hip_runtime.h>
#include <math.h>

typedef unsigned long long u64;
typedef unsigned int u32;
typedef unsigned short u16;
typedef unsigned char u8;

#define HH 512
#define WW 512
#define NIMG 96
#define NB 5

__global__ __launch_bounds__(64) void k_zero(int* __restrict__ c) {
    if (threadIdx.x < 32) c[threadIdx.x] = 0;
}

// =======================================================================
// A: sobel + NMS + thresholds -> u64 bitboards. Register-only stencil,
// 4-ROW BANDS for TLP. Lane owns 8 contiguous cols (C0 = lane*8).
// r10-r13: array state spills -> named scalars only.
// r14-r15: 8-row bands = 6144 waves -> occupancy 37%, VALUBusy 37%,
//   latency-bound (r5's 24576-wave kernel ran 58% busy). Fix: 4-row
//   bands -> 12288 waves (48 waves/CU demand, saturates 32/CU cap).
//   Compute macros unchanged from r15 (clean attribution).
// Output: per-row (weak|strong<<8) u16 to per-wave LDS slab; band-end
// 8x8 byte transpose (rows 0..3 active) -> one u64/plane/lane, coalesced.
// =======================================================================

#define DECL_HD(P) int P##H0,P##H1,P##H2,P##H3,P##H4,P##H5,P##H6,P##H7,P##H8,P##H9, \
                       P##D0,P##D1,P##D2,P##D3,P##D4,P##D5,P##D6,P##D7,P##D8,P##D9;
#define DECL_M(P)  int P##0,P##1,P##2,P##3,P##4,P##5,P##6,P##7,P##8,P##9;
#define DECL_Q(Q)  int Q##0,Q##1,Q##2,Q##3,Q##4,Q##5,Q##6,Q##7,Q##8,Q##9,Q##10,Q##11;

// load 12-pixel strip of row Yp into q-set Q (2x float4 + 2x float2 halo)
#define LOADQ(Q,Yp)  do {                                                  \
    int py_ = (Yp); py_ = py_ < 0 ? 0 : (py_ > HH - 1 ? HH - 1 : py_);     \
    const float* rp_ = img + ((size_t)py_ << 9) + C0;                      \
    float4 A_ = *(const float4*)rp_;                                       \
    float4 B_ = *(const float4*)(rp_ + 4);                                 \
    float2 L_ = *(const float2*)(rp_ + (lz ? 0 : -2));                     \
    float2 R_ = *(const float2*)(rp_ + (lw ? 6 : 8));                      \
    Q##2 = (int)(A_.x * 255.f); Q##3 = (int)(A_.y * 255.f);                \
    Q##4 = (int)(A_.z * 255.f); Q##5 = (int)(A_.w * 255.f);                \
    Q##6 = (int)(B_.x * 255.f); Q##7 = (int)(B_.y * 255.f);                \
    Q##8 = (int)(B_.z * 255.f); Q##9 = (int)(B_.w * 255.f);                \
    int l0_ = (int)(L_.x * 255.f), l1_ = (int)(L_.y * 255.f);              \
    int r0_ = (int)(R_.x * 255.f), r1_ = (int)(R_.y * 255.f);              \
    Q##0  = lz ? Q##2 : l0_;  Q##1  = lz ? Q##2 : l1_;                     \
    Q##10 = lw ? Q##9 : r0_;  Q##11 = lw ? Q##9 : r1_;                     \
  } while (0)

// H/D for one row (10 cols) from q-set Q, fully expanded
#define DHR1(P,Q,i,a,b,c) P##H##i = Q##a + 2 * Q##b + Q##c; P##D##i = Q##c - Q##a;
#define DHR(P,Q) do {                                                      \
    DHR1(P,Q,0,0,1,2)  DHR1(P,Q,1,1,2,3)  DHR1(P,Q,2,2,3,4)                \
    DHR1(P,Q,3,3,4,5)  DHR1(P,Q,4,4,5,6)  DHR1(P,Q,5,5,6,7)                \
    DHR1(P,Q,6,6,7,8)  DHR1(P,Q,7,7,8,9)  DHR1(P,Q,8,8,9,10)               \
    DHR1(P,Q,9,9,10,11)                                                    \
  } while (0)

// mag only (halo cols 0 and 9)
#define MAGC(PA,PB,PC,PM,i) {                                              \
    int gx_ = PA##D##i + 2 * PB##D##i + PC##D##i;                          \
    int gy_ = PC##H##i - PA##H##i;                                         \
    int u_ = gx_ < 0 ? -gx_ : gx_;                                         \
    int v_ = gy_ < 0 ? -gy_ : gy_;                                         \
    PM##i = u_ + v_; }

// mag + 2-bit dir code (own cols 1..8); squares via __mul24 (all < 2^24)
#define MAGCC(PA,PB,PC,PM,i,sh) {                                          \
    int gx_ = PA##D##i + 2 * PB##D##i + PC##D##i;                          \
    int gy_ = PC##H##i - PA##H##i;                                         \
    int u_ = gx_ < 0 ? -gx_ : gx_;                                         \
    int v_ = gy_ < 0 ? -gy_ : gy_;                                         \
    int mg_ = u_ + v_; PM##i = mg_;                                        \
    int a_ = (gy_ < 0) ? -gx_ : gx_;                                       \
    int qv_ = v_ - u_;                                                     \
    int t2_ = 2 * __mul24(u_, u_);                                         \
    int c_ = (a_ > 0) ? 1 : 3;                                             \
    if (qv_ > 0 && __mul24(qv_, qv_) > t2_) c_ = 2;                        \
    if (__mul24(mg_, mg_) < t2_) c_ = 0;                                   \
    cdv_ |= (u32)c_ << (sh); }

// PA = row m-1 (H,D), PB = row m (D), PC = row m+1 (H,D); writes PM, cd_
#define MAGR(PA,PB,PC,PM,ym_,cd_) do {                                     \
    u32 cdv_ = 0u;                                                         \
    if ((unsigned)(ym_) < (unsigned)HH) {                                  \
      MAGC(PA,PB,PC,PM,0)                                                  \
      MAGCC(PA,PB,PC,PM,1,0)  MAGCC(PA,PB,PC,PM,2,2)                       \
      MAGCC(PA,PB,PC,PM,3,4)  MAGCC(PA,PB,PC,PM,4,6)                       \
      MAGCC(PA,PB,PC,PM,5,8)  MAGCC(PA,PB,PC,PM,6,10)                      \
      MAGCC(PA,PB,PC,PM,7,12) MAGCC(PA,PB,PC,PM,8,14)                      \
      MAGC(PA,PB,PC,PM,9)                                                  \
      if (lz) PM##0 = 0;                                                   \
      if (lw) PM##9 = 0;                                                   \
    } else {                                                               \
      PM##0 = 0; PM##1 = 0; PM##2 = 0; PM##3 = 0; PM##4 = 0;               \
      PM##5 = 0; PM##6 = 0; PM##7 = 0; PM##8 = 0; PM##9 = 0;               \
    }                                                                      \
    cd_ = cdv_;                                                            \
  } while (0)

// classify one col: im/i/ip literal neighbor names, sh = 2*(bit), bi = bit
#define CLC(MA,MB,MC,im,i,ip,sh,bi) {                                      \
    int c_ = (int)((cdv_ >> (sh)) & 3u);                                   \
    int m0_ = MB##i;                                                       \
    int n1_ = (c_ == 0) ? MB##ip : (c_ == 1) ? MC##ip                      \
            : (c_ == 2) ? MC##i  : MC##im;                                 \
    int n2_ = (c_ == 0) ? MB##im : (c_ == 1) ? MA##im                      \
            : (c_ == 2) ? MA##i  : MA##ip;                                 \
    int nm_ = n1_ > n2_ ? n1_ : n2_;                                       \
    if (m0_ > 50 && m0_ >= nm_) {                                          \
      eB_ |= 1u << (bi);                                                   \
      if (m0_ > 150) sB_ |= 1u << (bi);                                    \
    } }

#define CLASSIFY(MA,MB,MC,cd_,ri_) do {                                    \
    u32 cdv_ = (cd_); u32 eB_ = 0u, sB_ = 0u;                              \
    CLC(MA,MB,MC,0,1,2,0,0)   CLC(MA,MB,MC,1,2,3,2,1)                      \
    CLC(MA,MB,MC,2,3,4,4,2)   CLC(MA,MB,MC,3,4,5,6,3)                      \
    CLC(MA,MB,MC,4,5,6,8,4)   CLC(MA,MB,MC,5,6,7,10,5)                     \
    CLC(MA,MB,MC,6,7,8,12,6)  CLC(MA,MB,MC,7,8,9,14,7)                     \
    SB[wv][ri_][lane] = (u16)(eB_ | (sB_ << 8));                           \
  } while (0)

// pipelined step: prefetch row into idle q-set, then compute on current set
#define PSTEP(ii,Qpre,Ypre,Qcur,HDs,PA,PB,PC,PM,MA,MB,MC) do {             \
    LOADQ(Qpre, (Ypre));                                                   \
    DHR(HDs, Qcur);                                                        \
    MAGR(PA,PB,PC,PM, Y0 + (ii) + 1, codeNext);                            \
    CLASSIFY(MA,MB,MC, codeCur, (ii)); codeCur = codeNext; } while (0)
#define LSTEP(ii,Qcur,HDs,PA,PB,PC,PM,MA,MB,MC) do {                       \
    DHR(HDs, Qcur);                                                        \
    MAGR(PA,PB,PC,PM, Y0 + (ii) + 1, codeNext);                            \
    CLASSIFY(MA,MB,MC, codeCur, (ii)); codeCur = codeNext; } while (0)

__global__ __launch_bounds__(256, 3) void k_sobel_bits(const float* __restrict__ in,
                                                       u64* __restrict__ Wg,
                                                       u64* __restrict__ Eg) {
    __shared__ u16 SB[4][4][72];   // [wave][row][lane], stride 72 for bank spread
    const int tid = threadIdx.x, wv = tid >> 6, lane = tid & 63;
    const int bid = blockIdx.x, z = bid >> 5, tq = bid & 31;
    const int Y0 = tq * 16 + wv * 4;          // 4-row band
    const int C0 = lane * 8;                  // 8 contiguous cols per lane
    const float* img = in + ((size_t)z << 18);
    const bool lz = (lane == 0), lw = (lane == 63);

    DECL_HD(HD0_) DECL_HD(HD1_) DECL_HD(HD2_)
    DECL_M(M0_) DECL_M(M1_) DECL_M(M2_)
    DECL_Q(qa) DECL_Q(qb)
    u32 codeCur, codeNext, cDump;

    // prologue (pipelined): row Y0+k -> HD slot (k+2)%3, q-set = parity(k)
    LOADQ(qa, Y0 - 2);
    LOADQ(qb, Y0 - 1);
    DHR(HD0_, qa);
    LOADQ(qa, Y0);
    DHR(HD1_, qb);
    LOADQ(qb, Y0 + 1);
    DHR(HD2_, qa);
    MAGR(HD0_,HD1_,HD2_,M0_, Y0 - 1, cDump);
    (void)cDump;
    LOADQ(qa, Y0 + 2);
    DHR(HD0_, qb);
    MAGR(HD1_,HD2_,HD0_,M1_, Y0, codeCur);

    // main sweep (classify rows Y0..Y0+3); prefetch row Y0+i+3 each step
    PSTEP(0, qb, Y0 + 3, qa, HD1_, HD2_,HD0_,HD1_, M2_, M0_,M1_,M2_);
    PSTEP(1, qa, Y0 + 4, qb, HD2_, HD0_,HD1_,HD2_, M0_, M1_,M2_,M0_);
    PSTEP(2, qb, Y0 + 5, qa, HD0_, HD1_,HD2_,HD0_, M1_, M2_,M0_,M1_);
    LSTEP(3,           qb, HD1_, HD2_,HD0_,HD1_, M2_, M0_,M1_,M2_);

    // epilogue: 8x8 byte transpose (rows 0..3 active; same-wave LDS) + store
    {
        const int gw = lane >> 3, r = lane & 7;
        if (r < 4) {
            const u16* sp = &SB[wv][r][gw << 3];     // 16B-aligned
            uint4 dd = *(const uint4*)sp;
            u32 wlo = __builtin_amdgcn_perm(dd.y, dd.x, 0x06040200u);
            u32 whi = __builtin_amdgcn_perm(dd.w, dd.z, 0x06040200u);
            u32 slo = __builtin_amdgcn_perm(dd.y, dd.x, 0x07050301u);
            u32 shi = __builtin_amdgcn_perm(dd.w, dd.z, 0x07050301u);
            const int Yr = Y0 + r;
            const size_t wa = (size_t)(z * 16 + (Yr >> 7) * 4 + (gw >> 1)) * 256
                            + (size_t)(Yr & 127) * 2 + (gw & 1);
            Wg[wa] = (u64)wlo | ((u64)whi << 32);
            Eg[wa] = (u64)slo | ((u64)shi << 32);
        }
    }
}

// =================== proven bit-domain hysteresis tail ===================

#define CONVERGE()                                                          \
    for (;;) {                                                              \
        if (tid == 0) s_any = 0;                                            \
        __syncthreads();                                                    \
        for (int slot = tid; slot < 260; slot += 256) {                     \
            int row_ = slot >> 1, w_ = slot & 1;                            \
            u64 E = Eb[row_][w_], Eo = Eb[row_][w_ ^ 1];                    \
            u64 h = E | (E << 1) | (E >> 1);                                \
            if (w_ == 0) h |= (u64)hLE[row_] | ((Eo & 1ull) << 63);         \
            else         h |= (Eo >> 63) | (((u64)hRE[row_]) << 63);        \
            Hb[row_][w_] = h;                                               \
        }                                                                   \
        __syncthreads();                                                    \
        {                                                                   \
            int row_ = (tid >> 1) + 1, w_ = tid & 1;                        \
            u64 W = Wb[row_][w_], E = Eb[row_][w_];                         \
            u64 nb = Hb[row_ - 1][w_] | Hb[row_ + 1][w_] | Hb[row_][w_];    \
            u64 En = E | (W & nb);                                          \
            for (;;) {                                                      \
                u64 E2 = En | (W & ((En << 1) | (En >> 1)));                \
                if (E2 == En) break;                                        \
                En = E2;                                                    \
            }                                                               \
            if (En != E) { Eb[row_][w_] = En; s_any = 1; }                  \
        }                                                                   \
        __syncthreads();                                                    \
        int f_ = s_any;                                                     \
        __syncthreads();                                                    \
        if (!f_) break;                                                     \
    }

#define LOAD_BIT_TILE(LOADW)                                                \
    const int bid = blockIdx.x, z = bid >> 4, t4 = bid & 15;                \
    const int ty = t4 >> 2, tx = t4 & 3;                                    \
    const size_t base = (size_t)bid * 256;                                  \
    const int row = tid >> 1, w = tid & 1;                                  \
    u64 E0 = Eg[base + tid];                                                \
    Eb[row + 1][w] = E0;                                                    \
    if (LOADW) Wb[row + 1][w] = Wg[base + tid];                             \
    if (tid < 128) {                                                        \
        u64 e = 0;                                                          \
        if (tx > 0) e = Eg[base - 256 + (size_t)tid * 2 + 1];               \
        hLE[tid + 1] = (u8)(e >> 63);                                       \
    } else {                                                                \
        int r_ = tid - 128;                                                 \
        u64 e = 0;                                                          \
        if (tx < 3) e = Eg[base + 256 + (size_t)r_ * 2];                    \
        hRE[r_ + 1] = (u8)(e & 1);                                          \
    }                                                                       \
    if (tid < 2) {                                                          \
        u64 e = 0; if (ty > 0) e = Eg[base - 1024 + 254 + tid];             \
        Eb[0][tid] = e;                                                     \
    } else if (tid < 4) {                                                   \
        u64 e = 0; if (ty < 3) e = Eg[base + 1024 + (tid - 2)];             \
        Eb[129][tid - 2] = e;                                               \
    } else if (tid == 4) {                                                  \
        u64 e = 0; if (ty > 0 && tx > 0) e = Eg[base - 1280 + 255];         \
        hLE[0] = (u8)(e >> 63);                                             \
    } else if (tid == 5) {                                                  \
        u64 e = 0; if (ty > 0 && tx < 3) e = Eg[base - 768 + 254];          \
        hRE[0] = (u8)(e & 1);                                               \
    } else if (tid == 6) {                                                  \
        u64 e = 0; if (ty < 3 && tx > 0) e = Eg[base + 768 + 1];            \
        hLE[129] = (u8)(e >> 63);                                           \
    } else if (tid == 7) {                                                  \
        u64 e = 0; if (ty < 3 && tx < 3) e = Eg[base + 1280];               \
        hRE[129] = (u8)(e & 1);                                             \
    }

__global__ __launch_bounds__(256) void k_hystbit(u64* __restrict__ Wg, u64* __restrict__ Eg,
                                                 int* __restrict__ counters, int pass) {
    if (pass > 0 && counters[pass - 1] == 0) return;
    __shared__ u64 Wb[130][2], Eb[130][2], Hb[130][2];
    __shared__ u8 hLE[130], hRE[130];
    __shared__ int s_any, s_chg;
    const int tid = threadIdx.x;
    if (tid == 0) s_chg = 0;

    LOAD_BIT_TILE(1)
    __syncthreads();

    CONVERGE();

    u64 En = Eb[row + 1][w];
    if (En != E0) { Eg[base + tid] = En; s_chg = 1; }
    __syncthreads();
    if (tid == 0 && s_chg) atomicAdd(&counters[pass], 1);
}

__global__ __launch_bounds__(256) void k_hystbit_final(u64* __restrict__ Wg,
                                                       u64* __restrict__ Eg,
                                                       float* __restrict__ outf) {
    __shared__ u64 Wb[130][2], Eb[130][2], Hb[130][2];
    __shared__ u8 hLE[130], hRE[130];
    __shared__ int s_any;
    const int tid = threadIdx.x;

    LOAD_BIT_TILE(1)
    (void)E0;
    __syncthreads();

    CONVERGE();

    const int y0 = ty * 128, x0 = tx * 128;
    float4* op = (float4*)(outf + (size_t)z * (HH * WW));
    const int rg = tid >> 5, cl = tid & 31;
    #pragma unroll
    for (int k = 0; k < 16; ++k) {
        int r = rg + (k << 3);
        u64 E = Eb[r + 1][cl >> 4];
        int b0 = (cl << 2) & 63;
        float4 v;
        v.x = (float)((E >> b0) & 1ull);
        v.y = (float)((E >> (b0 + 1)) & 1ull);
        v.z = (float)((E >> (b0 + 2)) & 1ull);
        v.w = (float)((E >> (b0 + 3)) & 1ull);
        op[((size_t)(y0 + r) * WW + x0 + (cl << 2)) >> 2] = v;
    }
}

extern "C" void kernel_launch(void* const* d_in, const int* in_sizes, int n_in,
                              void* d_out, int out_size, void* d_ws, size_t ws_size,
                              hipStream_t stream) {
    const float* in = (const float*)d_in[0];
    float* out = (float*)d_out;
    int* counters = (int*)d_ws;

    k_zero<<<1, 64, 0, stream>>>(counters);

    const size_t bbwords = (size_t)NIMG * 16 * 128 * 2;   // u64 words per plane
    u64* Wg = (u64*)((char*)d_ws + 256);
    u64* Eg = Wg + bbwords;

    dim3 gA(NIMG * 32);                 // 3072 blocks x 4 waves, 4-row bands
    k_sobel_bits<<<gA, 256, 0, stream>>>(in, Wg, Eg);

    dim3 gB(NIMG * 16);
    for (int p = 0; p < NB; ++p)
        k_hystbit<<<gB, 256, 0, stream>>>(Wg, Eg, counters, p);
    k_hystbit_final<<<gB, 256, 0, stream>>>(Wg, Eg, out);
}

// Round 17
// 101.096 us; speedup vs baseline: 1.0995x; 1.0995x over previous
//
#include <hip/hip_runtime.h>
#include <math.h>

typedef unsigned long long u64;
typedef unsigned int u32;
typedef unsigned short u16;
typedef unsigned char u8;

#define HH 512
#define WW 512
#define NIMG 96
#define NB 5

// =======================================================================
// A: sobel + NMS + thresholds -> u64 bitboards. Register-only stencil,
// 4-row bands, FLOAT-DOMAIN arithmetic (exact: all values are integers
// <= 4.2e6 < 2^24; quant floorf(f*255.f) is bit-identical to the
// reference's f32 floor(images*255)). Float wins vs int on CDNA:
//   mag = |gx|+|gy|  -> one v_add_f32 with abs input modifiers
//   qv  = |gy|-|gx|  -> one v_sub_f32 with abs modifiers
//   H/gx chains      -> FMA; no int-cvts anywhere.
// Bin-code sign test ((gx>0)!=(gy<0))?1:3 — the gx==0 mismatch vs the
// folded-half-plane definition is always overridden by the c=2 rule.
// r10-r13 lesson: named scalars only (array state spills wholesale).
// Block 0 also zeroes the pass counters (saves the k_zero launch).
// Output: per-row (weak|strong<<8) u16 to per-wave LDS slab; band-end
// 8x8 byte transpose -> one u64/plane/lane, coalesced 128B blocks.
// =======================================================================

#define DECL_HD(P) float P##H0,P##H1,P##H2,P##H3,P##H4,P##H5,P##H6,P##H7,P##H8,P##H9, \
                         P##D0,P##D1,P##D2,P##D3,P##D4,P##D5,P##D6,P##D7,P##D8,P##D9;
#define DECL_M(P)  float P##0,P##1,P##2,P##3,P##4,P##5,P##6,P##7,P##8,P##9;
#define DECL_Q(Q)  float Q##0,Q##1,Q##2,Q##3,Q##4,Q##5,Q##6,Q##7,Q##8,Q##9,Q##10,Q##11;

// load 12-pixel strip of row Yp into q-set Q (2x float4 + 2x float2 halo)
#define LOADQ(Q,Yp)  do {                                                  \
    int py_ = (Yp); py_ = py_ < 0 ? 0 : (py_ > HH - 1 ? HH - 1 : py_);     \
    const float* rp_ = img + ((size_t)py_ << 9) + C0;                      \
    float4 A_ = *(const float4*)rp_;                                       \
    float4 B_ = *(const float4*)(rp_ + 4);                                 \
    float2 L_ = *(const float2*)(rp_ + (lz ? 0 : -2));                     \
    float2 R_ = *(const float2*)(rp_ + (lw ? 6 : 8));                      \
    Q##2 = floorf(A_.x * 255.f); Q##3 = floorf(A_.y * 255.f);              \
    Q##4 = floorf(A_.z * 255.f); Q##5 = floorf(A_.w * 255.f);              \
    Q##6 = floorf(B_.x * 255.f); Q##7 = floorf(B_.y * 255.f);              \
    Q##8 = floorf(B_.z * 255.f); Q##9 = floorf(B_.w * 255.f);              \
    float l0_ = floorf(L_.x * 255.f), l1_ = floorf(L_.y * 255.f);          \
    float r0_ = floorf(R_.x * 255.f), r1_ = floorf(R_.y * 255.f);          \
    Q##0  = lz ? Q##2 : l0_;  Q##1  = lz ? Q##2 : l1_;                     \
    Q##10 = lw ? Q##9 : r0_;  Q##11 = lw ? Q##9 : r1_;                     \
  } while (0)

// H/D for one row (10 cols) from q-set Q, fully expanded
#define DHR1(P,Q,i,a,b,c) P##H##i = Q##a + 2.f * Q##b + Q##c; P##D##i = Q##c - Q##a;
#define DHR(P,Q) do {                                                      \
    DHR1(P,Q,0,0,1,2)  DHR1(P,Q,1,1,2,3)  DHR1(P,Q,2,2,3,4)                \
    DHR1(P,Q,3,3,4,5)  DHR1(P,Q,4,4,5,6)  DHR1(P,Q,5,5,6,7)                \
    DHR1(P,Q,6,6,7,8)  DHR1(P,Q,7,7,8,9)  DHR1(P,Q,8,8,9,10)               \
    DHR1(P,Q,9,9,10,11)                                                    \
  } while (0)

// mag only (halo cols 0 and 9)
#define MAGC(PA,PB,PC,PM,i) {                                              \
    float gx_ = PA##D##i + 2.f * PB##D##i + PC##D##i;                      \
    float gy_ = PC##H##i - PA##H##i;                                       \
    PM##i = fabsf(gx_) + fabsf(gy_); }

// mag + 2-bit dir code (own cols 1..8); all exact in f32 (< 2^24)
#define MAGCC(PA,PB,PC,PM,i,sh) {                                          \
    float gx_ = PA##D##i + 2.f * PB##D##i + PC##D##i;                      \
    float gy_ = PC##H##i - PA##H##i;                                       \
    float mg_ = fabsf(gx_) + fabsf(gy_); PM##i = mg_;                      \
    float u2_ = gx_ * gx_;                                                 \
    float t2_ = u2_ + u2_;                                                 \
    float qv_ = fabsf(gy_) - fabsf(gx_);                                   \
    int c_ = ((gx_ > 0.f) != (gy_ < 0.f)) ? 1 : 3;                         \
    if (qv_ > 0.f && qv_ * qv_ > t2_) c_ = 2;                              \
    if (mg_ * mg_ < t2_) c_ = 0;                                           \
    cdv_ |= (u32)c_ << (sh); }

// PA = row m-1 (H,D), PB = row m (D), PC = row m+1 (H,D); writes PM, cd_
#define MAGR(PA,PB,PC,PM,ym_,cd_) do {                                     \
    u32 cdv_ = 0u;                                                         \
    if ((unsigned)(ym_) < (unsigned)HH) {                                  \
      MAGC(PA,PB,PC,PM,0)                                                  \
      MAGCC(PA,PB,PC,PM,1,0)  MAGCC(PA,PB,PC,PM,2,2)                       \
      MAGCC(PA,PB,PC,PM,3,4)  MAGCC(PA,PB,PC,PM,4,6)                       \
      MAGCC(PA,PB,PC,PM,5,8)  MAGCC(PA,PB,PC,PM,6,10)                      \
      MAGCC(PA,PB,PC,PM,7,12) MAGCC(PA,PB,PC,PM,8,14)                      \
      MAGC(PA,PB,PC,PM,9)                                                  \
      if (lz) PM##0 = 0.f;                                                 \
      if (lw) PM##9 = 0.f;                                                 \
    } else {                                                               \
      PM##0 = 0.f; PM##1 = 0.f; PM##2 = 0.f; PM##3 = 0.f; PM##4 = 0.f;     \
      PM##5 = 0.f; PM##6 = 0.f; PM##7 = 0.f; PM##8 = 0.f; PM##9 = 0.f;     \
    }                                                                      \
    cd_ = cdv_;                                                            \
  } while (0)

// classify one col: im/i/ip literal neighbor names, sh = 2*(bit), bi = bit
#define CLC(MA,MB,MC,im,i,ip,sh,bi) {                                      \
    int c_ = (int)((cdv_ >> (sh)) & 3u);                                   \
    float m0_ = MB##i;                                                     \
    float n1_ = (c_ == 0) ? MB##ip : (c_ == 1) ? MC##ip                    \
            : (c_ == 2) ? MC##i  : MC##im;                                 \
    float n2_ = (c_ == 0) ? MB##im : (c_ == 1) ? MA##im                    \
            : (c_ == 2) ? MA##i  : MA##ip;                                 \
    float nm_ = fmaxf(n1_, n2_);                                           \
    if (m0_ > 50.f && m0_ >= nm_) {                                        \
      eB_ |= 1u << (bi);                                                   \
      if (m0_ > 150.f) sB_ |= 1u << (bi);                                  \
    } }

#define CLASSIFY(MA,MB,MC,cd_,ri_) do {                                    \
    u32 cdv_ = (cd_); u32 eB_ = 0u, sB_ = 0u;                              \
    CLC(MA,MB,MC,0,1,2,0,0)   CLC(MA,MB,MC,1,2,3,2,1)                      \
    CLC(MA,MB,MC,2,3,4,4,2)   CLC(MA,MB,MC,3,4,5,6,3)                      \
    CLC(MA,MB,MC,4,5,6,8,4)   CLC(MA,MB,MC,5,6,7,10,5)                     \
    CLC(MA,MB,MC,6,7,8,12,6)  CLC(MA,MB,MC,7,8,9,14,7)                     \
    SB[wv][ri_][lane] = (u16)(eB_ | (sB_ << 8));                           \
  } while (0)

// pipelined step: prefetch row into idle q-set, then compute on current set
#define PSTEP(ii,Qpre,Ypre,Qcur,HDs,PA,PB,PC,PM,MA,MB,MC) do {             \
    LOADQ(Qpre, (Ypre));                                                   \
    DHR(HDs, Qcur);                                                        \
    MAGR(PA,PB,PC,PM, Y0 + (ii) + 1, codeNext);                            \
    CLASSIFY(MA,MB,MC, codeCur, (ii)); codeCur = codeNext; } while (0)
#define LSTEP(ii,Qcur,HDs,PA,PB,PC,PM,MA,MB,MC) do {                       \
    DHR(HDs, Qcur);                                                        \
    MAGR(PA,PB,PC,PM, Y0 + (ii) + 1, codeNext);                            \
    CLASSIFY(MA,MB,MC, codeCur, (ii)); codeCur = codeNext; } while (0)

__global__ __launch_bounds__(256, 3) void k_sobel_bits(const float* __restrict__ in,
                                                       u64* __restrict__ Wg,
                                                       u64* __restrict__ Eg,
                                                       int* __restrict__ counters) {
    __shared__ u16 SB[4][4][72];   // [wave][row][lane], stride 72 for bank spread
    const int tid = threadIdx.x, wv = tid >> 6, lane = tid & 63;
    const int bid = blockIdx.x, z = bid >> 5, tq = bid & 31;
    if (bid == 0 && tid < 32) counters[tid] = 0;   // folded k_zero
    const int Y0 = tq * 16 + wv * 4;          // 4-row band
    const int C0 = lane * 8;                  // 8 contiguous cols per lane
    const float* img = in + ((size_t)z << 18);
    const bool lz = (lane == 0), lw = (lane == 63);

    DECL_HD(HD0_) DECL_HD(HD1_) DECL_HD(HD2_)
    DECL_M(M0_) DECL_M(M1_) DECL_M(M2_)
    DECL_Q(qa) DECL_Q(qb)
    u32 codeCur, codeNext, cDump;

    // prologue (pipelined): row Y0+k -> HD slot (k+2)%3, q-set = parity(k)
    LOADQ(qa, Y0 - 2);
    LOADQ(qb, Y0 - 1);
    DHR(HD0_, qa);
    LOADQ(qa, Y0);
    DHR(HD1_, qb);
    LOADQ(qb, Y0 + 1);
    DHR(HD2_, qa);
    MAGR(HD0_,HD1_,HD2_,M0_, Y0 - 1, cDump);
    (void)cDump;
    LOADQ(qa, Y0 + 2);
    DHR(HD0_, qb);
    MAGR(HD1_,HD2_,HD0_,M1_, Y0, codeCur);

    // main sweep (classify rows Y0..Y0+3); prefetch row Y0+i+3 each step
    PSTEP(0, qb, Y0 + 3, qa, HD1_, HD2_,HD0_,HD1_, M2_, M0_,M1_,M2_);
    PSTEP(1, qa, Y0 + 4, qb, HD2_, HD0_,HD1_,HD2_, M0_, M1_,M2_,M0_);
    PSTEP(2, qb, Y0 + 5, qa, HD0_, HD1_,HD2_,HD0_, M1_, M2_,M0_,M1_);
    LSTEP(3,           qb, HD1_, HD2_,HD0_,HD1_, M2_, M0_,M1_,M2_);

    // epilogue: 8x8 byte transpose (rows 0..3 active; same-wave LDS) + store
    {
        const int gw = lane >> 3, r = lane & 7;
        if (r < 4) {
            const u16* sp = &SB[wv][r][gw << 3];     // 16B-aligned
            uint4 dd = *(const uint4*)sp;
            u32 wlo = __builtin_amdgcn_perm(dd.y, dd.x, 0x06040200u);
            u32 whi = __builtin_amdgcn_perm(dd.w, dd.z, 0x06040200u);
            u32 slo = __builtin_amdgcn_perm(dd.y, dd.x, 0x07050301u);
            u32 shi = __builtin_amdgcn_perm(dd.w, dd.z, 0x07050301u);
            const int Yr = Y0 + r;
            const size_t wa = (size_t)(z * 16 + (Yr >> 7) * 4 + (gw >> 1)) * 256
                            + (size_t)(Yr & 127) * 2 + (gw & 1);
            Wg[wa] = (u64)wlo | ((u64)whi << 32);
            Eg[wa] = (u64)slo | ((u64)shi << 32);
        }
    }
}

// =================== proven bit-domain hysteresis tail ===================

#define CONVERGE()                                                          \
    for (;;) {                                                              \
        if (tid == 0) s_any = 0;                                            \
        __syncthreads();                                                    \
        for (int slot = tid; slot < 260; slot += 256) {                     \
            int row_ = slot >> 1, w_ = slot & 1;                            \
            u64 E = Eb[row_][w_], Eo = Eb[row_][w_ ^ 1];                    \
            u64 h = E | (E << 1) | (E >> 1);                                \
            if (w_ == 0) h |= (u64)hLE[row_] | ((Eo & 1ull) << 63);         \
            else         h |= (Eo >> 63) | (((u64)hRE[row_]) << 63);        \
            Hb[row_][w_] = h;                                               \
        }                                                                   \
        __syncthreads();                                                    \
        {                                                                   \
            int row_ = (tid >> 1) + 1, w_ = tid & 1;                        \
            u64 W = Wb[row_][w_], E = Eb[row_][w_];                         \
            u64 nb = Hb[row_ - 1][w_] | Hb[row_ + 1][w_] | Hb[row_][w_];    \
            u64 En = E | (W & nb);                                          \
            for (;;) {                                                      \
                u64 E2 = En | (W & ((En << 1) | (En >> 1)));                \
                if (E2 == En) break;                                        \
                En = E2;                                                    \
            }                                                               \
            if (En != E) { Eb[row_][w_] = En; s_any = 1; }                  \
        }                                                                   \
        __syncthreads();                                                    \
        int f_ = s_any;                                                     \
        __syncthreads();                                                    \
        if (!f_) break;                                                     \
    }

#define LOAD_BIT_TILE(LOADW)                                                \
    const int bid = blockIdx.x, z = bid >> 4, t4 = bid & 15;                \
    const int ty = t4 >> 2, tx = t4 & 3;                                    \
    const size_t base = (size_t)bid * 256;                                  \
    const int row = tid >> 1, w = tid & 1;                                  \
    u64 E0 = Eg[base + tid];                                                \
    Eb[row + 1][w] = E0;                                                    \
    if (LOADW) Wb[row + 1][w] = Wg[base + tid];                             \
    if (tid < 128) {                                                        \
        u64 e = 0;                                                          \
        if (tx > 0) e = Eg[base - 256 + (size_t)tid * 2 + 1];               \
        hLE[tid + 1] = (u8)(e >> 63);                                       \
    } else {                                                                \
        int r_ = tid - 128;                                                 \
        u64 e = 0;                                                          \
        if (tx < 3) e = Eg[base + 256 + (size_t)r_ * 2];                    \
        hRE[r_ + 1] = (u8)(e & 1);                                          \
    }                                                                       \
    if (tid < 2) {                                                          \
        u64 e = 0; if (ty > 0) e = Eg[base - 1024 + 254 + tid];             \
        Eb[0][tid] = e;                                                     \
    } else if (tid < 4) {                                                   \
        u64 e = 0; if (ty < 3) e = Eg[base + 1024 + (tid - 2)];             \
        Eb[129][tid - 2] = e;                                               \
    } else if (tid == 4) {                                                  \
        u64 e = 0; if (ty > 0 && tx > 0) e = Eg[base - 1280 + 255];         \
        hLE[0] = (u8)(e >> 63);                                             \
    } else if (tid == 5) {                                                  \
        u64 e = 0; if (ty > 0 && tx < 3) e = Eg[base - 768 + 254];          \
        hRE[0] = (u8)(e & 1);                                               \
    } else if (tid == 6) {                                                  \
        u64 e = 0; if (ty < 3 && tx > 0) e = Eg[base + 768 + 1];            \
        hLE[129] = (u8)(e >> 63);                                           \
    } else if (tid == 7) {                                                  \
        u64 e = 0; if (ty < 3 && tx < 3) e = Eg[base + 1280];               \
        hRE[129] = (u8)(e & 1);                                             \
    }

__global__ __launch_bounds__(256) void k_hystbit(u64* __restrict__ Wg, u64* __restrict__ Eg,
                                                 int* __restrict__ counters, int pass) {
    if (pass > 0 && counters[pass - 1] == 0) return;
    __shared__ u64 Wb[130][2], Eb[130][2], Hb[130][2];
    __shared__ u8 hLE[130], hRE[130];
    __shared__ int s_any, s_chg;
    const int tid = threadIdx.x;
    if (tid == 0) s_chg = 0;

    LOAD_BIT_TILE(1)
    __syncthreads();

    CONVERGE();

    u64 En = Eb[row + 1][w];
    if (En != E0) { Eg[base + tid] = En; s_chg = 1; }
    __syncthreads();
    if (tid == 0 && s_chg) atomicAdd(&counters[pass], 1);
}

__global__ __launch_bounds__(256) void k_hystbit_final(u64* __restrict__ Wg,
                                                       u64* __restrict__ Eg,
                                                       float* __restrict__ outf) {
    __shared__ u64 Wb[130][2], Eb[130][2], Hb[130][2];
    __shared__ u8 hLE[130], hRE[130];
    __shared__ int s_any;
    const int tid = threadIdx.x;

    LOAD_BIT_TILE(1)
    (void)E0;
    __syncthreads();

    CONVERGE();

    const int y0 = ty * 128, x0 = tx * 128;
    float4* op = (float4*)(outf + (size_t)z * (HH * WW));
    const int rg = tid >> 5, cl = tid & 31;
    #pragma unroll
    for (int k = 0; k < 16; ++k) {
        int r = rg + (k << 3);
        u64 E = Eb[r + 1][cl >> 4];
        int b0 = (cl << 2) & 63;
        float4 v;
        v.x = (float)((E >> b0) & 1ull);
        v.y = (float)((E >> (b0 + 1)) & 1ull);
        v.z = (float)((E >> (b0 + 2)) & 1ull);
        v.w = (float)((E >> (b0 + 3)) & 1ull);
        op[((size_t)(y0 + r) * WW + x0 + (cl << 2)) >> 2] = v;
    }
}

extern "C" void kernel_launch(void* const* d_in, const int* in_sizes, int n_in,
                              void* d_out, int out_size, void* d_ws, size_t ws_size,
                              hipStream_t stream) {
    const float* in = (const float*)d_in[0];
    float* out = (float*)d_out;
    int* counters = (int*)d_ws;

    const size_t bbwords = (size_t)NIMG * 16 * 128 * 2;   // u64 words per plane
    u64* Wg = (u64*)((char*)d_ws + 256);
    u64* Eg = Wg + bbwords;

    dim3 gA(NIMG * 32);                 // 3072 blocks x 4 waves, 4-row bands
    k_sobel_bits<<<gA, 256, 0, stream>>>(in, Wg, Eg, counters);

    dim3 gB(NIMG * 16);
    for (int p = 0; p < NB; ++p)
        k_hystbit<<<gB, 256, 0, stream>>>(Wg, Eg, counters, p);
    k_hystbit_final<<<gB, 256, 0, stream>>>(Wg, Eg, out);
}

// Round 18
// 100.684 us; speedup vs baseline: 1.1040x; 1.0041x over previous
//
#include <hip/hip_runtime.h>
#include <math.h>

typedef unsigned long long u64;
typedef unsigned int u32;
typedef unsigned short u16;
typedef unsigned char u8;

#define HH 512
#define WW 512
#define NIMG 96
#define NB 5

// =======================================================================
// A: sobel + NMS + thresholds -> u64 bitboards. Register-only stencil,
// 4-row bands, float-domain (exact: all values integers < 2^24).
// r17 lesson: VGPR 68 crossed the 64 boundary -> wave cap halved to
// 16/CU, occupancy 39->30%. This round: single q-set (r15 proved the
// explicit 2-set pipeline perf-neutral; saves 12 VGPR), plain
// __launch_bounds__(256) (named scalars stay resident - r14), and a
// no-code MAGRN for the prologue mag row (codes were discarded).
// Output: per-row (weak|strong<<8) u16 to per-wave LDS slab; band-end
// 8x8 byte transpose -> one u64/plane/lane, coalesced 128B blocks.
// =======================================================================

#define DECL_HD(P) float P##H0,P##H1,P##H2,P##H3,P##H4,P##H5,P##H6,P##H7,P##H8,P##H9, \
                         P##D0,P##D1,P##D2,P##D3,P##D4,P##D5,P##D6,P##D7,P##D8,P##D9;
#define DECL_M(P)  float P##0,P##1,P##2,P##3,P##4,P##5,P##6,P##7,P##8,P##9;

// load 12-pixel strip of row Yp into q0..q11 (2x float4 + 2x float2 halo)
#define LOADQ(Yp)  do {                                                    \
    int py_ = (Yp); py_ = py_ < 0 ? 0 : (py_ > HH - 1 ? HH - 1 : py_);     \
    const float* rp_ = img + ((size_t)py_ << 9) + C0;                      \
    float4 A_ = *(const float4*)rp_;                                       \
    float4 B_ = *(const float4*)(rp_ + 4);                                 \
    float2 L_ = *(const float2*)(rp_ + (lz ? 0 : -2));                     \
    float2 R_ = *(const float2*)(rp_ + (lw ? 6 : 8));                      \
    q2 = floorf(A_.x * 255.f); q3 = floorf(A_.y * 255.f);                  \
    q4 = floorf(A_.z * 255.f); q5 = floorf(A_.w * 255.f);                  \
    q6 = floorf(B_.x * 255.f); q7 = floorf(B_.y * 255.f);                  \
    q8 = floorf(B_.z * 255.f); q9 = floorf(B_.w * 255.f);                  \
    float l0_ = floorf(L_.x * 255.f), l1_ = floorf(L_.y * 255.f);          \
    float r0_ = floorf(R_.x * 255.f), r1_ = floorf(R_.y * 255.f);          \
    q0  = lz ? q2 : l0_;  q1  = lz ? q2 : l1_;                             \
    q10 = lw ? q9 : r0_;  q11 = lw ? q9 : r1_;                             \
  } while (0)

// H/D for one row (10 cols), fully expanded
#define DHR1(P,i,a,b,c) P##H##i = q##a + 2.f * q##b + q##c; P##D##i = q##c - q##a;
#define DHR(P) do {                                                        \
    DHR1(P,0,0,1,2)  DHR1(P,1,1,2,3)  DHR1(P,2,2,3,4)  DHR1(P,3,3,4,5)     \
    DHR1(P,4,4,5,6)  DHR1(P,5,5,6,7)  DHR1(P,6,6,7,8)  DHR1(P,7,7,8,9)     \
    DHR1(P,8,8,9,10) DHR1(P,9,9,10,11)                                     \
  } while (0)

// mag only
#define MAGC(PA,PB,PC,PM,i) {                                              \
    float gx_ = PA##D##i + 2.f * PB##D##i + PC##D##i;                      \
    float gy_ = PC##H##i - PA##H##i;                                       \
    PM##i = fabsf(gx_) + fabsf(gy_); }

// mag + 2-bit dir code (own cols 1..8); all exact in f32 (< 2^24)
#define MAGCC(PA,PB,PC,PM,i,sh) {                                          \
    float gx_ = PA##D##i + 2.f * PB##D##i + PC##D##i;                      \
    float gy_ = PC##H##i - PA##H##i;                                       \
    float mg_ = fabsf(gx_) + fabsf(gy_); PM##i = mg_;                      \
    float u2_ = gx_ * gx_;                                                 \
    float t2_ = u2_ + u2_;                                                 \
    float qv_ = fabsf(gy_) - fabsf(gx_);                                   \
    int c_ = ((gx_ > 0.f) != (gy_ < 0.f)) ? 1 : 3;                         \
    if (qv_ > 0.f && qv_ * qv_ > t2_) c_ = 2;                              \
    if (mg_ * mg_ < t2_) c_ = 0;                                           \
    cdv_ |= (u32)c_ << (sh); }

// full mag row with dir codes
#define MAGR(PA,PB,PC,PM,ym_,cd_) do {                                     \
    u32 cdv_ = 0u;                                                         \
    if ((unsigned)(ym_) < (unsigned)HH) {                                  \
      MAGC(PA,PB,PC,PM,0)                                                  \
      MAGCC(PA,PB,PC,PM,1,0)  MAGCC(PA,PB,PC,PM,2,2)                       \
      MAGCC(PA,PB,PC,PM,3,4)  MAGCC(PA,PB,PC,PM,4,6)                       \
      MAGCC(PA,PB,PC,PM,5,8)  MAGCC(PA,PB,PC,PM,6,10)                      \
      MAGCC(PA,PB,PC,PM,7,12) MAGCC(PA,PB,PC,PM,8,14)                      \
      MAGC(PA,PB,PC,PM,9)                                                  \
      if (lz) PM##0 = 0.f;                                                 \
      if (lw) PM##9 = 0.f;                                                 \
    } else {                                                               \
      PM##0 = 0.f; PM##1 = 0.f; PM##2 = 0.f; PM##3 = 0.f; PM##4 = 0.f;     \
      PM##5 = 0.f; PM##6 = 0.f; PM##7 = 0.f; PM##8 = 0.f; PM##9 = 0.f;     \
    }                                                                      \
    cd_ = cdv_;                                                            \
  } while (0)

// mag row WITHOUT dir codes (prologue row: codes unused)
#define MAGRN(PA,PB,PC,PM,ym_) do {                                        \
    if ((unsigned)(ym_) < (unsigned)HH) {                                  \
      MAGC(PA,PB,PC,PM,0) MAGC(PA,PB,PC,PM,1) MAGC(PA,PB,PC,PM,2)          \
      MAGC(PA,PB,PC,PM,3) MAGC(PA,PB,PC,PM,4) MAGC(PA,PB,PC,PM,5)          \
      MAGC(PA,PB,PC,PM,6) MAGC(PA,PB,PC,PM,7) MAGC(PA,PB,PC,PM,8)          \
      MAGC(PA,PB,PC,PM,9)                                                  \
      if (lz) PM##0 = 0.f;                                                 \
      if (lw) PM##9 = 0.f;                                                 \
    } else {                                                               \
      PM##0 = 0.f; PM##1 = 0.f; PM##2 = 0.f; PM##3 = 0.f; PM##4 = 0.f;     \
      PM##5 = 0.f; PM##6 = 0.f; PM##7 = 0.f; PM##8 = 0.f; PM##9 = 0.f;     \
    }                                                                      \
  } while (0)

// classify one col
#define CLC(MA,MB,MC,im,i,ip,sh,bi) {                                      \
    int c_ = (int)((cdv_ >> (sh)) & 3u);                                   \
    float m0_ = MB##i;                                                     \
    float n1_ = (c_ == 0) ? MB##ip : (c_ == 1) ? MC##ip                    \
            : (c_ == 2) ? MC##i  : MC##im;                                 \
    float n2_ = (c_ == 0) ? MB##im : (c_ == 1) ? MA##im                    \
            : (c_ == 2) ? MA##i  : MA##ip;                                 \
    float nm_ = fmaxf(n1_, n2_);                                           \
    if (m0_ > 50.f && m0_ >= nm_) {                                        \
      eB_ |= 1u << (bi);                                                   \
      if (m0_ > 150.f) sB_ |= 1u << (bi);                                  \
    } }

#define CLASSIFY(MA,MB,MC,cd_,ri_) do {                                    \
    u32 cdv_ = (cd_); u32 eB_ = 0u, sB_ = 0u;                              \
    CLC(MA,MB,MC,0,1,2,0,0)   CLC(MA,MB,MC,1,2,3,2,1)                      \
    CLC(MA,MB,MC,2,3,4,4,2)   CLC(MA,MB,MC,3,4,5,6,3)                      \
    CLC(MA,MB,MC,4,5,6,8,4)   CLC(MA,MB,MC,5,6,7,10,5)                     \
    CLC(MA,MB,MC,6,7,8,12,6)  CLC(MA,MB,MC,7,8,9,14,7)                     \
    SB[wv][ri_][lane] = (u16)(eB_ | (sB_ << 8));                           \
  } while (0)

// one sweep step: load next row, DHR into dead slot, mag, classify
#define STEP(ii,HDs,PA,PB,PC,PM,MA,MB,MC) do {                             \
    LOADQ(Y0 + (ii) + 2);                                                  \
    DHR(HDs);                                                              \
    MAGR(PA,PB,PC,PM, Y0 + (ii) + 1, codeNext);                            \
    CLASSIFY(MA,MB,MC, codeCur, (ii)); codeCur = codeNext; } while (0)

__global__ __launch_bounds__(256) void k_sobel_bits(const float* __restrict__ in,
                                                    u64* __restrict__ Wg,
                                                    u64* __restrict__ Eg,
                                                    int* __restrict__ counters) {
    __shared__ u16 SB[4][4][72];   // [wave][row][lane], stride 72 for bank spread
    const int tid = threadIdx.x, wv = tid >> 6, lane = tid & 63;
    const int bid = blockIdx.x, z = bid >> 5, tq = bid & 31;
    if (bid == 0 && tid < 32) counters[tid] = 0;   // folded k_zero
    const int Y0 = tq * 16 + wv * 4;          // 4-row band
    const int C0 = lane * 8;                  // 8 contiguous cols per lane
    const float* img = in + ((size_t)z << 18);
    const bool lz = (lane == 0), lw = (lane == 63);

    DECL_HD(HD0_) DECL_HD(HD1_) DECL_HD(HD2_)
    DECL_M(M0_) DECL_M(M1_) DECL_M(M2_)
    float q0, q1, q2, q3, q4, q5, q6, q7, q8, q9, q10, q11;
    u32 codeCur, codeNext;

    // prologue: DH rows Y0-2,Y0-1,Y0 -> slots 0,1,2 ; mag rows Y0-1,Y0
    LOADQ(Y0 - 2); DHR(HD0_);
    LOADQ(Y0 - 1); DHR(HD1_);
    LOADQ(Y0);     DHR(HD2_);
    MAGRN(HD0_,HD1_,HD2_,M0_, Y0 - 1);
    LOADQ(Y0 + 1); DHR(HD0_);                 // row Y0+1 -> slot 0
    MAGR(HD1_,HD2_,HD0_,M1_, Y0, codeCur);

    // main sweep (classify rows Y0..Y0+3)
    STEP(0, HD1_, HD2_,HD0_,HD1_, M2_, M0_,M1_,M2_);
    STEP(1, HD2_, HD0_,HD1_,HD2_, M0_, M1_,M2_,M0_);
    STEP(2, HD0_, HD1_,HD2_,HD0_, M1_, M2_,M0_,M1_);
    STEP(3, HD1_, HD2_,HD0_,HD1_, M2_, M0_,M1_,M2_);

    // epilogue: 8x8 byte transpose (rows 0..3 active; same-wave LDS) + store
    {
        const int gw = lane >> 3, r = lane & 7;
        if (r < 4) {
            const u16* sp = &SB[wv][r][gw << 3];     // 16B-aligned
            uint4 dd = *(const uint4*)sp;
            u32 wlo = __builtin_amdgcn_perm(dd.y, dd.x, 0x06040200u);
            u32 whi = __builtin_amdgcn_perm(dd.w, dd.z, 0x06040200u);
            u32 slo = __builtin_amdgcn_perm(dd.y, dd.x, 0x07050301u);
            u32 shi = __builtin_amdgcn_perm(dd.w, dd.z, 0x07050301u);
            const int Yr = Y0 + r;
            const size_t wa = (size_t)(z * 16 + (Yr >> 7) * 4 + (gw >> 1)) * 256
                            + (size_t)(Yr & 127) * 2 + (gw & 1);
            Wg[wa] = (u64)wlo | ((u64)whi << 32);
            Eg[wa] = (u64)slo | ((u64)shi << 32);
        }
    }
}

// =================== proven bit-domain hysteresis tail ===================

#define CONVERGE()                                                          \
    for (;;) {                                                              \
        if (tid == 0) s_any = 0;                                            \
        __syncthreads();                                                    \
        for (int slot = tid; slot < 260; slot += 256) {                     \
            int row_ = slot >> 1, w_ = slot & 1;                            \
            u64 E = Eb[row_][w_], Eo = Eb[row_][w_ ^ 1];                    \
            u64 h = E | (E << 1) | (E >> 1);                                \
            if (w_ == 0) h |= (u64)hLE[row_] | ((Eo & 1ull) << 63);         \
            else         h |= (Eo >> 63) | (((u64)hRE[row_]) << 63);        \
            Hb[row_][w_] = h;                                               \
        }                                                                   \
        __syncthreads();                                                    \
        {                                                                   \
            int row_ = (tid >> 1) + 1, w_ = tid & 1;                        \
            u64 W = Wb[row_][w_], E = Eb[row_][w_];                         \
            u64 nb = Hb[row_ - 1][w_] | Hb[row_ + 1][w_] | Hb[row_][w_];    \
            u64 En = E | (W & nb);                                          \
            for (;;) {                                                      \
                u64 E2 = En | (W & ((En << 1) | (En >> 1)));                \
                if (E2 == En) break;                                        \
                En = E2;                                                    \
            }                                                               \
            if (En != E) { Eb[row_][w_] = En; s_any = 1; }                  \
        }                                                                   \
        __syncthreads();                                                    \
        int f_ = s_any;                                                     \
        __syncthreads();                                                    \
        if (!f_) break;                                                     \
    }

#define LOAD_BIT_TILE(LOADW)                                                \
    const int bid = blockIdx.x, z = bid >> 4, t4 = bid & 15;                \
    const int ty = t4 >> 2, tx = t4 & 3;                                    \
    const size_t base = (size_t)bid * 256;                                  \
    const int row = tid >> 1, w = tid & 1;                                  \
    u64 E0 = Eg[base + tid];                                                \
    Eb[row + 1][w] = E0;                                                    \
    if (LOADW) Wb[row + 1][w] = Wg[base + tid];                             \
    if (tid < 128) {                                                        \
        u64 e = 0;                                                          \
        if (tx > 0) e = Eg[base - 256 + (size_t)tid * 2 + 1];               \
        hLE[tid + 1] = (u8)(e >> 63);                                       \
    } else {                                                                \
        int r_ = tid - 128;                                                 \
        u64 e = 0;                                                          \
        if (tx < 3) e = Eg[base + 256 + (size_t)r_ * 2];                    \
        hRE[r_ + 1] = (u8)(e & 1);                                          \
    }                                                                       \
    if (tid < 2) {                                                          \
        u64 e = 0; if (ty > 0) e = Eg[base - 1024 + 254 + tid];             \
        Eb[0][tid] = e;                                                     \
    } else if (tid < 4) {                                                   \
        u64 e = 0; if (ty < 3) e = Eg[base + 1024 + (tid - 2)];             \
        Eb[129][tid - 2] = e;                                               \
    } else if (tid == 4) {                                                  \
        u64 e = 0; if (ty > 0 && tx > 0) e = Eg[base - 1280 + 255];         \
        hLE[0] = (u8)(e >> 63);                                             \
    } else if (tid == 5) {                                                  \
        u64 e = 0; if (ty > 0 && tx < 3) e = Eg[base - 768 + 254];          \
        hRE[0] = (u8)(e & 1);                                               \
    } else if (tid == 6) {                                                  \
        u64 e = 0; if (ty < 3 && tx > 0) e = Eg[base + 768 + 1];            \
        hLE[129] = (u8)(e >> 63);                                           \
    } else if (tid == 7) {                                                  \
        u64 e = 0; if (ty < 3 && tx < 3) e = Eg[base + 1280];               \
        hRE[129] = (u8)(e & 1);                                             \
    }

__global__ __launch_bounds__(256) void k_hystbit(u64* __restrict__ Wg, u64* __restrict__ Eg,
                                                 int* __restrict__ counters, int pass) {
    if (pass > 0 && counters[pass - 1] == 0) return;
    __shared__ u64 Wb[130][2], Eb[130][2], Hb[130][2];
    __shared__ u8 hLE[130], hRE[130];
    __shared__ int s_any, s_chg;
    const int tid = threadIdx.x;
    if (tid == 0) s_chg = 0;

    LOAD_BIT_TILE(1)
    __syncthreads();

    CONVERGE();

    u64 En = Eb[row + 1][w];
    if (En != E0) { Eg[base + tid] = En; s_chg = 1; }
    __syncthreads();
    if (tid == 0 && s_chg) atomicAdd(&counters[pass], 1);
}

__global__ __launch_bounds__(256) void k_hystbit_final(u64* __restrict__ Wg,
                                                       u64* __restrict__ Eg,
                                                       float* __restrict__ outf) {
    __shared__ u64 Wb[130][2], Eb[130][2], Hb[130][2];
    __shared__ u8 hLE[130], hRE[130];
    __shared__ int s_any;
    const int tid = threadIdx.x;

    LOAD_BIT_TILE(1)
    (void)E0;
    __syncthreads();

    CONVERGE();

    const int y0 = ty * 128, x0 = tx * 128;
    float4* op = (float4*)(outf + (size_t)z * (HH * WW));
    const int rg = tid >> 5, cl = tid & 31;
    #pragma unroll
    for (int k = 0; k < 16; ++k) {
        int r = rg + (k << 3);
        u64 E = Eb[r + 1][cl >> 4];
        int b0 = (cl << 2) & 63;
        float4 v;
        v.x = (float)((E >> b0) & 1ull);
        v.y = (float)((E >> (b0 + 1)) & 1ull);
        v.z = (float)((E >> (b0 + 2)) & 1ull);
        v.w = (float)((E >> (b0 + 3)) & 1ull);
        op[((size_t)(y0 + r) * WW + x0 + (cl << 2)) >> 2] = v;
    }
}

extern "C" void kernel_launch(void* const* d_in, const int* in_sizes, int n_in,
                              void* d_out, int out_size, void* d_ws, size_t ws_size,
                              hipStream_t stream) {
    const float* in = (const float*)d_in[0];
    float* out = (float*)d_out;
    int* counters = (int*)d_ws;

    const size_t bbwords = (size_t)NIMG * 16 * 128 * 2;   // u64 words per plane
    u64* Wg = (u64*)((char*)d_ws + 256);
    u64* Eg = Wg + bbwords;

    dim3 gA(NIMG * 32);                 // 3072 blocks x 4 waves, 4-row bands
    k_sobel_bits<<<gA, 256, 0, stream>>>(in, Wg, Eg, counters);

    dim3 gB(NIMG * 16);
    for (int p = 0; p < NB; ++p)
        k_hystbit<<<gB, 256, 0, stream>>>(Wg, Eg, counters, p);
    k_hystbit_final<<<gB, 256, 0, stream>>>(Wg, Eg, out);
}

// Round 19
// 99.738 us; speedup vs baseline: 1.1145x; 1.0095x over previous
//
#include <hip/hip_runtime.h>
#include <math.h>

typedef unsigned long long u64;
typedef unsigned int u32;
typedef unsigned short u16;
typedef unsigned char u8;

#define HH 512
#define WW 512
#define NIMG 96
#define NB 5

// =======================================================================
// A: sobel + NMS + thresholds -> u64 bitboards. Register-only stencil,
// 4-row bands, float-domain (exact: all values integers < 2^24),
// SHUFFLE-HALO: the wave spans the full 512-col row (lane owns 8 cols),
// so all horizontal halo data comes from adjacent lanes via __shfl:
//   pixels: pl = shfl_up(p7), pr = shfl_down(p0)  (drops 2 loads/row)
//   mags:   M_L = shfl_up(M7), M_R = shfl_down(M0) (drops 2 DHR cols +
//           2 halo-mag computations per row)
// Border lanes: replicate for pixels (lz/lw cndmask), zero for NMS mags.
// r10-r13: named scalars only. r17: stay under 64 VGPR.
// Output: per-row (weak|strong<<8) u16 to per-wave LDS slab; band-end
// 8x8 byte transpose -> one u64/plane/lane, coalesced 128B blocks.
// =======================================================================

#define DECL_HD(P) float P##H0,P##H1,P##H2,P##H3,P##H4,P##H5,P##H6,P##H7, \
                         P##D0,P##D1,P##D2,P##D3,P##D4,P##D5,P##D6,P##D7;
#define DECL_M(P)  float P##0,P##1,P##2,P##3,P##4,P##5,P##6,P##7,P##L,P##R;

// load own 8 pixels of row Yp (2x float4), quantize, shfl halo pair
#define LOADP(Yp)  do {                                                    \
    int py_ = (Yp); py_ = py_ < 0 ? 0 : (py_ > HH - 1 ? HH - 1 : py_);     \
    const float* rp_ = img + ((size_t)py_ << 9) + C0;                      \
    float4 A_ = *(const float4*)rp_;                                       \
    float4 B_ = *(const float4*)(rp_ + 4);                                 \
    p0 = floorf(A_.x * 255.f); p1 = floorf(A_.y * 255.f);                  \
    p2 = floorf(A_.z * 255.f); p3 = floorf(A_.w * 255.f);                  \
    p4 = floorf(B_.x * 255.f); p5 = floorf(B_.y * 255.f);                  \
    p6 = floorf(B_.z * 255.f); p7 = floorf(B_.w * 255.f);                  \
    pl = __shfl_up(p7, 1);  if (lz) pl = p0;                               \
    pr = __shfl_down(p0, 1); if (lw) pr = p7;                              \
  } while (0)

// H/D for own 8 cols
#define DHR(P) do {                                                        \
    P##H0 = pl + 2.f * p0 + p1; P##D0 = p1 - pl;                           \
    P##H1 = p0 + 2.f * p1 + p2; P##D1 = p2 - p0;                           \
    P##H2 = p1 + 2.f * p2 + p3; P##D2 = p3 - p1;                           \
    P##H3 = p2 + 2.f * p3 + p4; P##D3 = p4 - p2;                           \
    P##H4 = p3 + 2.f * p4 + p5; P##D4 = p5 - p3;                           \
    P##H5 = p4 + 2.f * p5 + p6; P##D5 = p6 - p4;                           \
    P##H6 = p5 + 2.f * p6 + p7; P##D6 = p7 - p5;                           \
    P##H7 = p6 + 2.f * p7 + pr; P##D7 = pr - p6;                           \
  } while (0)

// mag only (prologue row)
#define MAGCO(PA,PB,PC,PM,i) {                                             \
    float gx_ = PA##D##i + 2.f * PB##D##i + PC##D##i;                      \
    float gy_ = PC##H##i - PA##H##i;                                       \
    PM##i = fabsf(gx_) + fabsf(gy_); }

// mag + 2-bit dir code; all exact in f32 (< 2^24)
#define MAGCC(PA,PB,PC,PM,i,sh) {                                          \
    float gx_ = PA##D##i + 2.f * PB##D##i + PC##D##i;                      \
    float gy_ = PC##H##i - PA##H##i;                                       \
    float mg_ = fabsf(gx_) + fabsf(gy_); PM##i = mg_;                      \
    float u2_ = gx_ * gx_;                                                 \
    float t2_ = u2_ + u2_;                                                 \
    float qv_ = fabsf(gy_) - fabsf(gx_);                                   \
    int c_ = ((gx_ > 0.f) != (gy_ < 0.f)) ? 1 : 3;                         \
    if (qv_ > 0.f && qv_ * qv_ > t2_) c_ = 2;                              \
    if (mg_ * mg_ < t2_) c_ = 0;                                           \
    cdv_ |= (u32)c_ << (sh); }

// halo mags via shfl (0 at image x-borders); row-validity is wave-uniform
#define MAGHALO(PM) do {                                                   \
    PM##L = __shfl_up(PM##7, 1);  if (lz) PM##L = 0.f;                     \
    PM##R = __shfl_down(PM##0, 1); if (lw) PM##R = 0.f;                    \
  } while (0)

#define MAGZERO(PM) do {                                                   \
    PM##0 = 0.f; PM##1 = 0.f; PM##2 = 0.f; PM##3 = 0.f;                    \
    PM##4 = 0.f; PM##5 = 0.f; PM##6 = 0.f; PM##7 = 0.f;                    \
    PM##L = 0.f; PM##R = 0.f;                                              \
  } while (0)

// full mag row with dir codes
#define MAGR(PA,PB,PC,PM,ym_,cd_) do {                                     \
    u32 cdv_ = 0u;                                                         \
    if ((unsigned)(ym_) < (unsigned)HH) {                                  \
      MAGCC(PA,PB,PC,PM,0,0)   MAGCC(PA,PB,PC,PM,1,2)                      \
      MAGCC(PA,PB,PC,PM,2,4)   MAGCC(PA,PB,PC,PM,3,6)                      \
      MAGCC(PA,PB,PC,PM,4,8)   MAGCC(PA,PB,PC,PM,5,10)                     \
      MAGCC(PA,PB,PC,PM,6,12)  MAGCC(PA,PB,PC,PM,7,14)                     \
      MAGHALO(PM);                                                         \
    } else { MAGZERO(PM); }                                                \
    cd_ = cdv_;                                                            \
  } while (0)

// mag row WITHOUT dir codes (prologue row)
#define MAGRN(PA,PB,PC,PM,ym_) do {                                        \
    if ((unsigned)(ym_) < (unsigned)HH) {                                  \
      MAGCO(PA,PB,PC,PM,0) MAGCO(PA,PB,PC,PM,1) MAGCO(PA,PB,PC,PM,2)       \
      MAGCO(PA,PB,PC,PM,3) MAGCO(PA,PB,PC,PM,4) MAGCO(PA,PB,PC,PM,5)       \
      MAGCO(PA,PB,PC,PM,6) MAGCO(PA,PB,PC,PM,7)                            \
      MAGHALO(PM);                                                         \
    } else { MAGZERO(PM); }                                                \
  } while (0)

// classify one col, fully general operand names
#define CLCX(q1a,q1b,q1c,q1d,q2a,q2b,q2c,q2d,m0v,sh,bi) {                  \
    int c_ = (int)((cdv_ >> (sh)) & 3u);                                   \
    float n1_ = (c_ == 0) ? (q1a) : (c_ == 1) ? (q1b)                      \
              : (c_ == 2) ? (q1c) : (q1d);                                 \
    float n2_ = (c_ == 0) ? (q2a) : (c_ == 1) ? (q2b)                      \
              : (c_ == 2) ? (q2c) : (q2d);                                 \
    float nm_ = fmaxf(n1_, n2_);                                           \
    if ((m0v) > 50.f && (m0v) >= nm_) {                                    \
      eB_ |= 1u << (bi);                                                   \
      if ((m0v) > 150.f) sB_ |= 1u << (bi);                                \
    } }

#define CLCM(MA,MB,MC,im,i,ip,sh,bi)                                       \
    CLCX(MB##ip, MC##ip, MC##i, MC##im, MB##im, MA##im, MA##i, MA##ip,     \
         MB##i, sh, bi)

#define CLASSIFY(MA,MB,MC,cd_,ri_) do {                                    \
    u32 cdv_ = (cd_); u32 eB_ = 0u, sB_ = 0u;                              \
    CLCX(MB##1, MC##1, MC##0, MC##L, MB##L, MA##L, MA##0, MA##1,           \
         MB##0, 0, 0)                                                      \
    CLCM(MA,MB,MC,0,1,2,2,1)   CLCM(MA,MB,MC,1,2,3,4,2)                    \
    CLCM(MA,MB,MC,2,3,4,6,3)   CLCM(MA,MB,MC,3,4,5,8,4)                    \
    CLCM(MA,MB,MC,4,5,6,10,5)  CLCM(MA,MB,MC,5,6,7,12,6)                   \
    CLCX(MB##R, MC##R, MC##7, MC##6, MB##6, MA##6, MA##7, MA##R,           \
         MB##7, 14, 7)                                                     \
    SB[wv][ri_][lane] = (u16)(eB_ | (sB_ << 8));                           \
  } while (0)

// one sweep step: load next row, DHR into dead slot, mag, classify
#define STEP(ii,HDs,PA,PB,PC,PM,MA,MB,MC) do {                             \
    LOADP(Y0 + (ii) + 2);                                                  \
    DHR(HDs);                                                              \
    MAGR(PA,PB,PC,PM, Y0 + (ii) + 1, codeNext);                            \
    CLASSIFY(MA,MB,MC, codeCur, (ii)); codeCur = codeNext; } while (0)

__global__ __launch_bounds__(256) void k_sobel_bits(const float* __restrict__ in,
                                                    u64* __restrict__ Wg,
                                                    u64* __restrict__ Eg,
                                                    int* __restrict__ counters) {
    __shared__ u16 SB[4][4][72];   // [wave][row][lane], stride 72 for bank spread
    const int tid = threadIdx.x, wv = tid >> 6, lane = tid & 63;
    const int bid = blockIdx.x, z = bid >> 5, tq = bid & 31;
    if (bid == 0 && tid < 32) counters[tid] = 0;   // folded k_zero
    const int Y0 = tq * 16 + wv * 4;          // 4-row band
    const int C0 = lane * 8;                  // 8 contiguous cols per lane
    const float* img = in + ((size_t)z << 18);
    const bool lz = (lane == 0), lw = (lane == 63);

    DECL_HD(HD0_) DECL_HD(HD1_) DECL_HD(HD2_)
    DECL_M(M0_) DECL_M(M1_) DECL_M(M2_)
    float p0, p1, p2, p3, p4, p5, p6, p7, pl, pr;
    u32 codeCur, codeNext;

    // prologue: DH rows Y0-2,Y0-1,Y0 -> slots 0,1,2 ; mag rows Y0-1,Y0
    LOADP(Y0 - 2); DHR(HD0_);
    LOADP(Y0 - 1); DHR(HD1_);
    LOADP(Y0);     DHR(HD2_);
    MAGRN(HD0_,HD1_,HD2_,M0_, Y0 - 1);
    LOADP(Y0 + 1); DHR(HD0_);                 // row Y0+1 -> slot 0
    MAGR(HD1_,HD2_,HD0_,M1_, Y0, codeCur);

    // main sweep (classify rows Y0..Y0+3)
    STEP(0, HD1_, HD2_,HD0_,HD1_, M2_, M0_,M1_,M2_);
    STEP(1, HD2_, HD0_,HD1_,HD2_, M0_, M1_,M2_,M0_);
    STEP(2, HD0_, HD1_,HD2_,HD0_, M1_, M2_,M0_,M1_);
    STEP(3, HD1_, HD2_,HD0_,HD1_, M2_, M0_,M1_,M2_);

    // epilogue: 8x8 byte transpose (rows 0..3 active; same-wave LDS) + store
    {
        const int gw = lane >> 3, r = lane & 7;
        if (r < 4) {
            const u16* sp = &SB[wv][r][gw << 3];     // 16B-aligned
            uint4 dd = *(const uint4*)sp;
            u32 wlo = __builtin_amdgcn_perm(dd.y, dd.x, 0x06040200u);
            u32 whi = __builtin_amdgcn_perm(dd.w, dd.z, 0x06040200u);
            u32 slo = __builtin_amdgcn_perm(dd.y, dd.x, 0x07050301u);
            u32 shi = __builtin_amdgcn_perm(dd.w, dd.z, 0x07050301u);
            const int Yr = Y0 + r;
            const size_t wa = (size_t)(z * 16 + (Yr >> 7) * 4 + (gw >> 1)) * 256
                            + (size_t)(Yr & 127) * 2 + (gw & 1);
            Wg[wa] = (u64)wlo | ((u64)whi << 32);
            Eg[wa] = (u64)slo | ((u64)shi << 32);
        }
    }
}

// =================== proven bit-domain hysteresis tail ===================

#define CONVERGE()                                                          \
    for (;;) {                                                              \
        if (tid == 0) s_any = 0;                                            \
        __syncthreads();                                                    \
        for (int slot = tid; slot < 260; slot += 256) {                     \
            int row_ = slot >> 1, w_ = slot & 1;                            \
            u64 E = Eb[row_][w_], Eo = Eb[row_][w_ ^ 1];                    \
            u64 h = E | (E << 1) | (E >> 1);                                \
            if (w_ == 0) h |= (u64)hLE[row_] | ((Eo & 1ull) << 63);         \
            else         h |= (Eo >> 63) | (((u64)hRE[row_]) << 63);        \
            Hb[row_][w_] = h;                                               \
        }                                                                   \
        __syncthreads();                                                    \
        {                                                                   \
            int row_ = (tid >> 1) + 1, w_ = tid & 1;                        \
            u64 W = Wb[row_][w_], E = Eb[row_][w_];                         \
            u64 nb = Hb[row_ - 1][w_] | Hb[row_ + 1][w_] | Hb[row_][w_];    \
            u64 En = E | (W & nb);                                          \
            for (;;) {                                                      \
                u64 E2 = En | (W & ((En << 1) | (En >> 1)));                \
                if (E2 == En) break;                                        \
                En = E2;                                                    \
            }                                                               \
            if (En != E) { Eb[row_][w_] = En; s_any = 1; }                  \
        }                                                                   \
        __syncthreads();                                                    \
        int f_ = s_any;                                                     \
        __syncthreads();                                                    \
        if (!f_) break;                                                     \
    }

#define LOAD_BIT_TILE(LOADW)                                                \
    const int bid = blockIdx.x, z = bid >> 4, t4 = bid & 15;                \
    const int ty = t4 >> 2, tx = t4 & 3;                                    \
    const size_t base = (size_t)bid * 256;                                  \
    const int row = tid >> 1, w = tid & 1;                                  \
    u64 E0 = Eg[base + tid];                                                \
    Eb[row + 1][w] = E0;                                                    \
    if (LOADW) Wb[row + 1][w] = Wg[base + tid];                             \
    if (tid < 128) {                                                        \
        u64 e = 0;                                                          \
        if (tx > 0) e = Eg[base - 256 + (size_t)tid * 2 + 1];               \
        hLE[tid + 1] = (u8)(e >> 63);                                       \
    } else {                                                                \
        int r_ = tid - 128;                                                 \
        u64 e = 0;                                                          \
        if (tx < 3) e = Eg[base + 256 + (size_t)r_ * 2];                    \
        hRE[r_ + 1] = (u8)(e & 1);                                          \
    }                                                                       \
    if (tid < 2) {                                                          \
        u64 e = 0; if (ty > 0) e = Eg[base - 1024 + 254 + tid];             \
        Eb[0][tid] = e;                                                     \
    } else if (tid < 4) {                                                   \
        u64 e = 0; if (ty < 3) e = Eg[base + 1024 + (tid - 2)];             \
        Eb[129][tid - 2] = e;                                               \
    } else if (tid == 4) {                                                  \
        u64 e = 0; if (ty > 0 && tx > 0) e = Eg[base - 1280 + 255];         \
        hLE[0] = (u8)(e >> 63);                                             \
    } else if (tid == 5) {                                                  \
        u64 e = 0; if (ty > 0 && tx < 3) e = Eg[base - 768 + 254];          \
        hRE[0] = (u8)(e & 1);                                               \
    } else if (tid == 6) {                                                  \
        u64 e = 0; if (ty < 3 && tx > 0) e = Eg[base + 768 + 1];            \
        hLE[129] = (u8)(e >> 63);                                           \
    } else if (tid == 7) {                                                  \
        u64 e = 0; if (ty < 3 && tx < 3) e = Eg[base + 1280];               \
        hRE[129] = (u8)(e & 1);                                             \
    }

__global__ __launch_bounds__(256) void k_hystbit(u64* __restrict__ Wg, u64* __restrict__ Eg,
                                                 int* __restrict__ counters, int pass) {
    if (pass > 0 && counters[pass - 1] == 0) return;
    __shared__ u64 Wb[130][2], Eb[130][2], Hb[130][2];
    __shared__ u8 hLE[130], hRE[130];
    __shared__ int s_any, s_chg;
    const int tid = threadIdx.x;
    if (tid == 0) s_chg = 0;

    LOAD_BIT_TILE(1)
    __syncthreads();

    CONVERGE();

    u64 En = Eb[row + 1][w];
    if (En != E0) { Eg[base + tid] = En; s_chg = 1; }
    __syncthreads();
    if (tid == 0 && s_chg) atomicAdd(&counters[pass], 1);
}

__global__ __launch_bounds__(256) void k_hystbit_final(u64* __restrict__ Wg,
                                                       u64* __restrict__ Eg,
                                                       float* __restrict__ outf) {
    __shared__ u64 Wb[130][2], Eb[130][2], Hb[130][2];
    __shared__ u8 hLE[130], hRE[130];
    __shared__ int s_any;
    const int tid = threadIdx.x;

    LOAD_BIT_TILE(1)
    (void)E0;
    __syncthreads();

    CONVERGE();

    const int y0 = ty * 128, x0 = tx * 128;
    float4* op = (float4*)(outf + (size_t)z * (HH * WW));
    const int rg = tid >> 5, cl = tid & 31;
    #pragma unroll
    for (int k = 0; k < 16; ++k) {
        int r = rg + (k << 3);
        u64 E = Eb[r + 1][cl >> 4];
        int b0 = (cl << 2) & 63;
        float4 v;
        v.x = (float)((E >> b0) & 1ull);
        v.y = (float)((E >> (b0 + 1)) & 1ull);
        v.z = (float)((E >> (b0 + 2)) & 1ull);
        v.w = (float)((E >> (b0 + 3)) & 1ull);
        op[((size_t)(y0 + r) * WW + x0 + (cl << 2)) >> 2] = v;
    }
}

extern "C" void kernel_launch(void* const* d_in, const int* in_sizes, int n_in,
                              void* d_out, int out_size, void* d_ws, size_t ws_size,
                              hipStream_t stream) {
    const float* in = (const float*)d_in[0];
    float* out = (float*)d_out;
    int* counters = (int*)d_ws;

    const size_t bbwords = (size_t)NIMG * 16 * 128 * 2;   // u64 words per plane
    u64* Wg = (u64*)((char*)d_ws + 256);
    u64* Eg = Wg + bbwords;

    dim3 gA(NIMG * 32);                 // 3072 blocks x 4 waves, 4-row bands
    k_sobel_bits<<<gA, 256, 0, stream>>>(in, Wg, Eg, counters);

    dim3 gB(NIMG * 16);
    for (int p = 0; p < NB; ++p)
        k_hystbit<<<gB, 256, 0, stream>>>(Wg, Eg, counters, p);
    k_hystbit_final<<<gB, 256, 0, stream>>>(Wg, Eg, out);
}

// Round 20
// 95.029 us; speedup vs baseline: 1.1697x; 1.0496x over previous
//
#include <hip/hip_runtime.h>
#include <math.h>

typedef unsigned long long u64;
typedef unsigned int u32;
typedef unsigned short u16;
typedef unsigned char u8;

#define HH 512
#define WW 512
#define NIMG 96
#define NB 5

// =======================================================================
// A: sobel + NMS + thresholds -> u64 bitboards. Register-only stencil,
// 4-row bands, float-domain, shuffle-halo (r19), now BATCH-LOADED:
// all 8 band rows are loaded up front into 8 named float sets (64 VGPR)
// followed by sched_barrier(0) so the scheduler CANNOT sink them to
// their uses (r15/r19 lesson: given the chance, the RA flattens any
// software pipeline to save registers, exposing ~8 full HBM latencies
// per wave; r19 = 78us with only 33us busy). Quantize+halo-shfl happen
// at consumption. __launch_bounds__(256,4): 128-VGPR budget, no spill
// (peak live ~115 named scalars; r10-13: arrays spill, scalars don't).
// Output: per-row (weak|strong<<8) u16 to per-wave LDS slab; band-end
// 8x8 byte transpose -> one u64/plane/lane, coalesced 128B blocks.
// =======================================================================

#define DECL_HD(P) float P##H0,P##H1,P##H2,P##H3,P##H4,P##H5,P##H6,P##H7, \
                         P##D0,P##D1,P##D2,P##D3,P##D4,P##D5,P##D6,P##D7;
#define DECL_M(P)  float P##0,P##1,P##2,P##3,P##4,P##5,P##6,P##7,P##L,P##R;
#define DECL_P(P)  float P##0,P##1,P##2,P##3,P##4,P##5,P##6,P##7;

// raw load of own 8 pixels of row Yp (2x float4) into named set P
#define LOADR(P,Yp)  do {                                                  \
    int py_ = (Yp); py_ = py_ < 0 ? 0 : (py_ > HH - 1 ? HH - 1 : py_);     \
    const float* rp_ = img + ((size_t)py_ << 9) + C0;                      \
    float4 A_ = *(const float4*)rp_;                                       \
    float4 B_ = *(const float4*)(rp_ + 4);                                 \
    P##0 = A_.x; P##1 = A_.y; P##2 = A_.z; P##3 = A_.w;                    \
    P##4 = B_.x; P##5 = B_.y; P##6 = B_.z; P##7 = B_.w;                    \
  } while (0)

// quantize set P + halo shfl + H/D for own 8 cols into slot HP
#define QDHR(HP,P) do {                                                    \
    float s0_ = floorf(P##0 * 255.f), s1_ = floorf(P##1 * 255.f);          \
    float s2_ = floorf(P##2 * 255.f), s3_ = floorf(P##3 * 255.f);          \
    float s4_ = floorf(P##4 * 255.f), s5_ = floorf(P##5 * 255.f);          \
    float s6_ = floorf(P##6 * 255.f), s7_ = floorf(P##7 * 255.f);          \
    float pl_ = __shfl_up(s7_, 1);   if (lz) pl_ = s0_;                    \
    float pr_ = __shfl_down(s0_, 1); if (lw) pr_ = s7_;                    \
    HP##H0 = pl_ + 2.f * s0_ + s1_; HP##D0 = s1_ - pl_;                    \
    HP##H1 = s0_ + 2.f * s1_ + s2_; HP##D1 = s2_ - s0_;                    \
    HP##H2 = s1_ + 2.f * s2_ + s3_; HP##D2 = s3_ - s1_;                    \
    HP##H3 = s2_ + 2.f * s3_ + s4_; HP##D3 = s4_ - s2_;                    \
    HP##H4 = s3_ + 2.f * s4_ + s5_; HP##D4 = s5_ - s3_;                    \
    HP##H5 = s4_ + 2.f * s5_ + s6_; HP##D5 = s6_ - s4_;                    \
    HP##H6 = s5_ + 2.f * s6_ + s7_; HP##D6 = s7_ - s5_;                    \
    HP##H7 = s6_ + 2.f * s7_ + pr_; HP##D7 = pr_ - s6_;                    \
  } while (0)

// mag only (prologue row)
#define MAGCO(PA,PB,PC,PM,i) {                                             \
    float gx_ = PA##D##i + 2.f * PB##D##i + PC##D##i;                      \
    float gy_ = PC##H##i - PA##H##i;                                       \
    PM##i = fabsf(gx_) + fabsf(gy_); }

// mag + 2-bit dir code; all exact in f32 (< 2^24)
#define MAGCC(PA,PB,PC,PM,i,sh) {                                          \
    float gx_ = PA##D##i + 2.f * PB##D##i + PC##D##i;                      \
    float gy_ = PC##H##i - PA##H##i;                                       \
    float mg_ = fabsf(gx_) + fabsf(gy_); PM##i = mg_;                      \
    float u2_ = gx_ * gx_;                                                 \
    float t2_ = u2_ + u2_;                                                 \
    float qv_ = fabsf(gy_) - fabsf(gx_);                                   \
    int c_ = ((gx_ > 0.f) != (gy_ < 0.f)) ? 1 : 3;                         \
    if (qv_ > 0.f && qv_ * qv_ > t2_) c_ = 2;                              \
    if (mg_ * mg_ < t2_) c_ = 0;                                           \
    cdv_ |= (u32)c_ << (sh); }

// halo mags via shfl (0 at image x-borders); row-validity is wave-uniform
#define MAGHALO(PM) do {                                                   \
    PM##L = __shfl_up(PM##7, 1);  if (lz) PM##L = 0.f;                     \
    PM##R = __shfl_down(PM##0, 1); if (lw) PM##R = 0.f;                    \
  } while (0)

#define MAGZERO(PM) do {                                                   \
    PM##0 = 0.f; PM##1 = 0.f; PM##2 = 0.f; PM##3 = 0.f;                    \
    PM##4 = 0.f; PM##5 = 0.f; PM##6 = 0.f; PM##7 = 0.f;                    \
    PM##L = 0.f; PM##R = 0.f;                                              \
  } while (0)

// full mag row with dir codes
#define MAGR(PA,PB,PC,PM,ym_,cd_) do {                                     \
    u32 cdv_ = 0u;                                                         \
    if ((unsigned)(ym_) < (unsigned)HH) {                                  \
      MAGCC(PA,PB,PC,PM,0,0)   MAGCC(PA,PB,PC,PM,1,2)                      \
      MAGCC(PA,PB,PC,PM,2,4)   MAGCC(PA,PB,PC,PM,3,6)                      \
      MAGCC(PA,PB,PC,PM,4,8)   MAGCC(PA,PB,PC,PM,5,10)                     \
      MAGCC(PA,PB,PC,PM,6,12)  MAGCC(PA,PB,PC,PM,7,14)                     \
      MAGHALO(PM);                                                         \
    } else { MAGZERO(PM); }                                                \
    cd_ = cdv_;                                                            \
  } while (0)

// mag row WITHOUT dir codes (prologue row)
#define MAGRN(PA,PB,PC,PM,ym_) do {                                        \
    if ((unsigned)(ym_) < (unsigned)HH) {                                  \
      MAGCO(PA,PB,PC,PM,0) MAGCO(PA,PB,PC,PM,1) MAGCO(PA,PB,PC,PM,2)       \
      MAGCO(PA,PB,PC,PM,3) MAGCO(PA,PB,PC,PM,4) MAGCO(PA,PB,PC,PM,5)       \
      MAGCO(PA,PB,PC,PM,6) MAGCO(PA,PB,PC,PM,7)                            \
      MAGHALO(PM);                                                         \
    } else { MAGZERO(PM); }                                                \
  } while (0)

// classify one col, fully general operand names
#define CLCX(q1a,q1b,q1c,q1d,q2a,q2b,q2c,q2d,m0v,sh,bi) {                  \
    int c_ = (int)((cdv_ >> (sh)) & 3u);                                   \
    float n1_ = (c_ == 0) ? (q1a) : (c_ == 1) ? (q1b)                      \
              : (c_ == 2) ? (q1c) : (q1d);                                 \
    float n2_ = (c_ == 0) ? (q2a) : (c_ == 1) ? (q2b)                      \
              : (c_ == 2) ? (q2c) : (q2d);                                 \
    float nm_ = fmaxf(n1_, n2_);                                           \
    if ((m0v) > 50.f && (m0v) >= nm_) {                                    \
      eB_ |= 1u << (bi);                                                   \
      if ((m0v) > 150.f) sB_ |= 1u << (bi);                                \
    } }

#define CLCM(MA,MB,MC,im,i,ip,sh,bi)                                       \
    CLCX(MB##ip, MC##ip, MC##i, MC##im, MB##im, MA##im, MA##i, MA##ip,     \
         MB##i, sh, bi)

#define CLASSIFY(MA,MB,MC,cd_,ri_) do {                                    \
    u32 cdv_ = (cd_); u32 eB_ = 0u, sB_ = 0u;                              \
    CLCX(MB##1, MC##1, MC##0, MC##L, MB##L, MA##L, MA##0, MA##1,           \
         MB##0, 0, 0)                                                      \
    CLCM(MA,MB,MC,0,1,2,2,1)   CLCM(MA,MB,MC,1,2,3,4,2)                    \
    CLCM(MA,MB,MC,2,3,4,6,3)   CLCM(MA,MB,MC,3,4,5,8,4)                    \
    CLCM(MA,MB,MC,4,5,6,10,5)  CLCM(MA,MB,MC,5,6,7,12,6)                   \
    CLCX(MB##R, MC##R, MC##7, MC##6, MB##6, MA##6, MA##7, MA##R,           \
         MB##7, 14, 7)                                                     \
    SB[wv][ri_][lane] = (u16)(eB_ | (sB_ << 8));                           \
  } while (0)

// one sweep step: consume preloaded set PSET, mag, classify
#define STEP(ii,HDs,PSET,PA,PB,PC,PM,MA,MB,MC) do {                        \
    QDHR(HDs, PSET);                                                       \
    MAGR(PA,PB,PC,PM, Y0 + (ii) + 1, codeNext);                            \
    CLASSIFY(MA,MB,MC, codeCur, (ii)); codeCur = codeNext; } while (0)

__global__ __launch_bounds__(256, 4) void k_sobel_bits(const float* __restrict__ in,
                                                       u64* __restrict__ Wg,
                                                       u64* __restrict__ Eg,
                                                       int* __restrict__ counters) {
    __shared__ u16 SB[4][4][72];   // [wave][row][lane], stride 72 for bank spread
    const int tid = threadIdx.x, wv = tid >> 6, lane = tid & 63;
    const int bid = blockIdx.x, z = bid >> 5, tq = bid & 31;
    if (bid == 0 && tid < 32) counters[tid] = 0;   // folded k_zero
    const int Y0 = tq * 16 + wv * 4;          // 4-row band
    const int C0 = lane * 8;                  // 8 contiguous cols per lane
    const float* img = in + ((size_t)z << 18);
    const bool lz = (lane == 0), lw = (lane == 63);

    DECL_HD(HD0_) DECL_HD(HD1_) DECL_HD(HD2_)
    DECL_M(M0_) DECL_M(M1_) DECL_M(M2_)
    DECL_P(pA) DECL_P(pB) DECL_P(pC) DECL_P(pD)
    DECL_P(pE) DECL_P(pF) DECL_P(pG) DECL_P(pH)
    u32 codeCur, codeNext;

    // ---- batch-issue ALL 8 row loads; sched_barrier pins them here ----
    LOADR(pA, Y0 - 2); LOADR(pB, Y0 - 1); LOADR(pC, Y0);     LOADR(pD, Y0 + 1);
    LOADR(pE, Y0 + 2); LOADR(pF, Y0 + 3); LOADR(pG, Y0 + 4); LOADR(pH, Y0 + 5);
    __builtin_amdgcn_sched_barrier(0);

    // prologue: DH rows Y0-2,Y0-1,Y0 -> slots 0,1,2 ; mag rows Y0-1,Y0
    QDHR(HD0_, pA);
    QDHR(HD1_, pB);
    QDHR(HD2_, pC);
    MAGRN(HD0_,HD1_,HD2_,M0_, Y0 - 1);
    QDHR(HD0_, pD);                           // row Y0+1 -> slot 0
    MAGR(HD1_,HD2_,HD0_,M1_, Y0, codeCur);

    // main sweep (classify rows Y0..Y0+3)
    STEP(0, HD1_, pE, HD2_,HD0_,HD1_, M2_, M0_,M1_,M2_);
    STEP(1, HD2_, pF, HD0_,HD1_,HD2_, M0_, M1_,M2_,M0_);
    STEP(2, HD0_, pG, HD1_,HD2_,HD0_, M1_, M2_,M0_,M1_);
    STEP(3, HD1_, pH, HD2_,HD0_,HD1_, M2_, M0_,M1_,M2_);

    // epilogue: 8x8 byte transpose (rows 0..3 active; same-wave LDS) + store
    {
        const int gw = lane >> 3, r = lane & 7;
        if (r < 4) {
            const u16* sp = &SB[wv][r][gw << 3];     // 16B-aligned
            uint4 dd = *(const uint4*)sp;
            u32 wlo = __builtin_amdgcn_perm(dd.y, dd.x, 0x06040200u);
            u32 whi = __builtin_amdgcn_perm(dd.w, dd.z, 0x06040200u);
            u32 slo = __builtin_amdgcn_perm(dd.y, dd.x, 0x07050301u);
            u32 shi = __builtin_amdgcn_perm(dd.w, dd.z, 0x07050301u);
            const int Yr = Y0 + r;
            const size_t wa = (size_t)(z * 16 + (Yr >> 7) * 4 + (gw >> 1)) * 256
                            + (size_t)(Yr & 127) * 2 + (gw & 1);
            Wg[wa] = (u64)wlo | ((u64)whi << 32);
            Eg[wa] = (u64)slo | ((u64)shi << 32);
        }
    }
}

// =================== proven bit-domain hysteresis tail ===================

#define CONVERGE()                                                          \
    for (;;) {                                                              \
        if (tid == 0) s_any = 0;                                            \
        __syncthreads();                                                    \
        for (int slot = tid; slot < 260; slot += 256) {                     \
            int row_ = slot >> 1, w_ = slot & 1;                            \
            u64 E = Eb[row_][w_], Eo = Eb[row_][w_ ^ 1];                    \
            u64 h = E | (E << 1) | (E >> 1);                                \
            if (w_ == 0) h |= (u64)hLE[row_] | ((Eo & 1ull) << 63);         \
            else         h |= (Eo >> 63) | (((u64)hRE[row_]) << 63);        \
            Hb[row_][w_] = h;                                               \
        }                                                                   \
        __syncthreads();                                                    \
        {                                                                   \
            int row_ = (tid >> 1) + 1, w_ = tid & 1;                        \
            u64 W = Wb[row_][w_], E = Eb[row_][w_];                         \
            u64 nb = Hb[row_ - 1][w_] | Hb[row_ + 1][w_] | Hb[row_][w_];    \
            u64 En = E | (W & nb);                                          \
            for (;;) {                                                      \
                u64 E2 = En | (W & ((En << 1) | (En >> 1)));                \
                if (E2 == En) break;                                        \
                En = E2;                                                    \
            }                                                               \
            if (En != E) { Eb[row_][w_] = En; s_any = 1; }                  \
        }                                                                   \
        __syncthreads();                                                    \
        int f_ = s_any;                                                     \
        __syncthreads();                                                    \
        if (!f_) break;                                                     \
    }

#define LOAD_BIT_TILE(LOADW)                                                \
    const int bid = blockIdx.x, z = bid >> 4, t4 = bid & 15;                \
    const int ty = t4 >> 2, tx = t4 & 3;                                    \
    const size_t base = (size_t)bid * 256;                                  \
    const int row = tid >> 1, w = tid & 1;                                  \
    u64 E0 = Eg[base + tid];                                                \
    Eb[row + 1][w] = E0;                                                    \
    if (LOADW) Wb[row + 1][w] = Wg[base + tid];                             \
    if (tid < 128) {                                                        \
        u64 e = 0;                                                          \
        if (tx > 0) e = Eg[base - 256 + (size_t)tid * 2 + 1];               \
        hLE[tid + 1] = (u8)(e >> 63);                                       \
    } else {                                                                \
        int r_ = tid - 128;                                                 \
        u64 e = 0;                                                          \
        if (tx < 3) e = Eg[base + 256 + (size_t)r_ * 2];                    \
        hRE[r_ + 1] = (u8)(e & 1);                                          \
    }                                                                       \
    if (tid < 2) {                                                          \
        u64 e = 0; if (ty > 0) e = Eg[base - 1024 + 254 + tid];             \
        Eb[0][tid] = e;                                                     \
    } else if (tid < 4) {                                                   \
        u64 e = 0; if (ty < 3) e = Eg[base + 1024 + (tid - 2)];             \
        Eb[129][tid - 2] = e;                                               \
    } else if (tid == 4) {                                                  \
        u64 e = 0; if (ty > 0 && tx > 0) e = Eg[base - 1280 + 255];         \
        hLE[0] = (u8)(e >> 63);                                             \
    } else if (tid == 5) {                                                  \
        u64 e = 0; if (ty > 0 && tx < 3) e = Eg[base - 768 + 254];          \
        hRE[0] = (u8)(e & 1);                                               \
    } else if (tid == 6) {                                                  \
        u64 e = 0; if (ty < 3 && tx > 0) e = Eg[base + 768 + 1];            \
        hLE[129] = (u8)(e >> 63);                                           \
    } else if (tid == 7) {                                                  \
        u64 e = 0; if (ty < 3 && tx < 3) e = Eg[base + 1280];               \
        hRE[129] = (u8)(e & 1);                                             \
    }

__global__ __launch_bounds__(256) void k_hystbit(u64* __restrict__ Wg, u64* __restrict__ Eg,
                                                 int* __restrict__ counters, int pass) {
    if (pass > 0 && counters[pass - 1] == 0) return;
    __shared__ u64 Wb[130][2], Eb[130][2], Hb[130][2];
    __shared__ u8 hLE[130], hRE[130];
    __shared__ int s_any, s_chg;
    const int tid = threadIdx.x;
    if (tid == 0) s_chg = 0;

    LOAD_BIT_TILE(1)
    __syncthreads();

    CONVERGE();

    u64 En = Eb[row + 1][w];
    if (En != E0) { Eg[base + tid] = En; s_chg = 1; }
    __syncthreads();
    if (tid == 0 && s_chg) atomicAdd(&counters[pass], 1);
}

__global__ __launch_bounds__(256) void k_hystbit_final(u64* __restrict__ Wg,
                                                       u64* __restrict__ Eg,
                                                       float* __restrict__ outf) {
    __shared__ u64 Wb[130][2], Eb[130][2], Hb[130][2];
    __shared__ u8 hLE[130], hRE[130];
    __shared__ int s_any;
    const int tid = threadIdx.x;

    LOAD_BIT_TILE(1)
    (void)E0;
    __syncthreads();

    CONVERGE();

    const int y0 = ty * 128, x0 = tx * 128;
    float4* op = (float4*)(outf + (size_t)z * (HH * WW));
    const int rg = tid >> 5, cl = tid & 31;
    #pragma unroll
    for (int k = 0; k < 16; ++k) {
        int r = rg + (k << 3);
        u64 E = Eb[r + 1][cl >> 4];
        int b0 = (cl << 2) & 63;
        float4 v;
        v.x = (float)((E >> b0) & 1ull);
        v.y = (float)((E >> (b0 + 1)) & 1ull);
        v.z = (float)((E >> (b0 + 2)) & 1ull);
        v.w = (float)((E >> (b0 + 3)) & 1ull);
        op[((size_t)(y0 + r) * WW + x0 + (cl << 2)) >> 2] = v;
    }
}

extern "C" void kernel_launch(void* const* d_in, const int* in_sizes, int n_in,
                              void* d_out, int out_size, void* d_ws, size_t ws_size,
                              hipStream_t stream) {
    const float* in = (const float*)d_in[0];
    float* out = (float*)d_out;
    int* counters = (int*)d_ws;

    const size_t bbwords = (size_t)NIMG * 16 * 128 * 2;   // u64 words per plane
    u64* Wg = (u64*)((char*)d_ws + 256);
    u64* Eg = Wg + bbwords;

    dim3 gA(NIMG * 32);                 // 3072 blocks x 4 waves, 4-row bands
    k_sobel_bits<<<gA, 256, 0, stream>>>(in, Wg, Eg, counters);

    dim3 gB(NIMG * 16);
    for (int p = 0; p < NB; ++p)
        k_hystbit<<<gB, 256, 0, stream>>>(Wg, Eg, counters, p);
    k_hystbit_final<<<gB, 256, 0, stream>>>(Wg, Eg, out);
}